// Round 2
// baseline (384.287 us; speedup 1.0000x reference)
//
#include <hip/hip_runtime.h>

#define BB 8
#define LL 8192
#define DD 1024
#define ROWS_PER_ITER 4

// One block per batch. 1024 threads, 8 mask elements per thread (2x int4).
// Block-wide exclusive scan -> destination slot for every input position,
// inverse permutation perm[b*S + dest] = src for dest < S, float 0/1 mask out.
__global__ __launch_bounds__(1024) void build_perm(
    const int* __restrict__ mask, int* __restrict__ perm,
    float* __restrict__ mask_out, int S) {
  const int b = blockIdx.x;
  const int t = threadIdx.x;          // 0..1023
  const int lane = t & 63;
  const int wave = t >> 6;            // 0..15

  __shared__ int wave_sums[16];
  __shared__ int s_total;

  const int* m = mask + (size_t)b * LL;
  const int base_i = t * 8;

  // Vectorized mask load: 2x int4 (32 B per thread, aligned).
  int4 mv0 = ((const int4*)(m + base_i))[0];
  int4 mv1 = ((const int4*)(m + base_i))[1];
  int vals[8] = {mv0.x ? 1 : 0, mv0.y ? 1 : 0, mv0.z ? 1 : 0, mv0.w ? 1 : 0,
                 mv1.x ? 1 : 0, mv1.y ? 1 : 0, mv1.z ? 1 : 0, mv1.w ? 1 : 0};
  int local = 0;
#pragma unroll
  for (int k = 0; k < 8; ++k) local += vals[k];

  // Wave-level inclusive scan of per-thread sums (wave = 64 lanes).
  int incl = local;
#pragma unroll
  for (int off = 1; off < 64; off <<= 1) {
    int up = __shfl_up(incl, off, 64);
    if (lane >= off) incl += up;
  }
  if (lane == 63) wave_sums[wave] = incl;
  __syncthreads();

  // Scan the 16 wave sums in wave 0.
  if (wave == 0 && lane < 16) {
    int v = wave_sums[lane];
#pragma unroll
    for (int off = 1; off < 16; off <<= 1) {
      int up = __shfl_up(v, off, 64);
      if (lane >= off) v += up;
    }
    wave_sums[lane] = v;
    if (lane == 15) s_total = v;
  }
  __syncthreads();

  const int wave_base = (wave == 0) ? 0 : wave_sums[wave - 1];
  const int num_tokens = s_total;
  int run = wave_base + incl - local;  // exclusive count of trues before base_i

#pragma unroll
  for (int k = 0; k < 8; ++k) {
    const int i = base_i + k;
    int dest;
    if (vals[k]) {
      dest = run;                      // rank among true tokens
      run += 1;
    } else {
      dest = num_tokens + (i - run);   // trues first, then falses in order
    }
    if (dest < S) perm[(size_t)b * S + dest] = i;
  }

  // Validity mask output as float 0/1.
  for (int j = t; j < S; j += 1024) {
    mask_out[(size_t)b * S + j] = (j < num_tokens) ? 1.0f : 0.0f;
  }
}

// Grid-stride gather: grid = (256, B), 256 threads/block.
// Each block iteration copies ROWS_PER_ITER rows (4 KB each); all perm loads
// and row loads are issued before any store (MLP to hide the dependent chain).
__global__ __launch_bounds__(256) void gather_rows(
    const float* __restrict__ hidden, const int* __restrict__ perm,
    float* __restrict__ out, int S) {
  const int b = blockIdx.y;
  const int t = threadIdx.x;  // 0..255, one float4 slot of a row
  const float* __restrict__ src_base = hidden + (size_t)b * LL * DD;
  float* __restrict__ dst_base = out + (size_t)b * S * DD;
  const int* __restrict__ perm_b = perm + (size_t)b * S;
  const int stride = gridDim.x * ROWS_PER_ITER;

  for (int r0 = blockIdx.x * ROWS_PER_ITER; r0 < S; r0 += stride) {
    int srcs[ROWS_PER_ITER];
#pragma unroll
    for (int u = 0; u < ROWS_PER_ITER; ++u) {
      const int r = r0 + u;
      srcs[u] = (r < S) ? perm_b[r] : -1;
    }
    float4 v[ROWS_PER_ITER];
#pragma unroll
    for (int u = 0; u < ROWS_PER_ITER; ++u) {
      if (srcs[u] >= 0)
        v[u] = ((const float4*)(src_base + (size_t)srcs[u] * DD))[t];
    }
#pragma unroll
    for (int u = 0; u < ROWS_PER_ITER; ++u) {
      const int r = r0 + u;
      if (r < S)
        ((float4*)(dst_base + (size_t)r * DD))[t] = v[u];
    }
  }
}

extern "C" void kernel_launch(void* const* d_in, const int* in_sizes, int n_in,
                              void* d_out, int out_size, void* d_ws, size_t ws_size,
                              hipStream_t stream) {
  const float* hidden = (const float*)d_in[0];
  const int* mask = (const int*)d_in[1];

  // out_size = B*S*D + B*S  ->  S = out_size / (B*(D+1))
  const int S = out_size / (BB * (DD + 1));

  float* out_hidden = (float*)d_out;
  float* out_mask = out_hidden + (size_t)BB * S * DD;
  int* perm = (int*)d_ws;  // B*S ints

  build_perm<<<BB, 1024, 0, stream>>>(mask, perm, out_mask, S);
  gather_rows<<<dim3(256, BB), 256, 0, stream>>>(hidden, perm, out_hidden, S);
}

// Round 4
// 354.699 us; speedup vs baseline: 1.0834x; 1.0834x over previous
//
#include <hip/hip_runtime.h>

#define BB 8
#define LL 8192
#define DD 1024

typedef float nfloat4 __attribute__((ext_vector_type(4)));

// One block per batch. 1024 threads, 8 mask elements per thread (2x int4).
// Block-wide exclusive scan -> destination slot for every input position,
// inverse permutation perm[b*S + dest] = src for dest < S, float 0/1 mask out.
__global__ __launch_bounds__(1024) void build_perm(
    const int* __restrict__ mask, int* __restrict__ perm,
    float* __restrict__ mask_out, int S) {
  const int b = blockIdx.x;
  const int t = threadIdx.x;          // 0..1023
  const int lane = t & 63;
  const int wave = t >> 6;            // 0..15

  __shared__ int wave_sums[16];
  __shared__ int s_total;

  const int* m = mask + (size_t)b * LL;
  const int base_i = t * 8;

  // Vectorized mask load: 2x int4 (32 B per thread, aligned).
  int4 mv0 = ((const int4*)(m + base_i))[0];
  int4 mv1 = ((const int4*)(m + base_i))[1];
  int vals[8] = {mv0.x ? 1 : 0, mv0.y ? 1 : 0, mv0.z ? 1 : 0, mv0.w ? 1 : 0,
                 mv1.x ? 1 : 0, mv1.y ? 1 : 0, mv1.z ? 1 : 0, mv1.w ? 1 : 0};
  int local = 0;
#pragma unroll
  for (int k = 0; k < 8; ++k) local += vals[k];

  // Wave-level inclusive scan of per-thread sums (wave = 64 lanes).
  int incl = local;
#pragma unroll
  for (int off = 1; off < 64; off <<= 1) {
    int up = __shfl_up(incl, off, 64);
    if (lane >= off) incl += up;
  }
  if (lane == 63) wave_sums[wave] = incl;
  __syncthreads();

  // Scan the 16 wave sums in wave 0.
  if (wave == 0 && lane < 16) {
    int v = wave_sums[lane];
#pragma unroll
    for (int off = 1; off < 16; off <<= 1) {
      int up = __shfl_up(v, off, 64);
      if (lane >= off) v += up;
    }
    wave_sums[lane] = v;
    if (lane == 15) s_total = v;
  }
  __syncthreads();

  const int wave_base = (wave == 0) ? 0 : wave_sums[wave - 1];
  const int num_tokens = s_total;
  int run = wave_base + incl - local;  // exclusive count of trues before base_i

#pragma unroll
  for (int k = 0; k < 8; ++k) {
    const int i = base_i + k;
    int dest;
    if (vals[k]) {
      dest = run;                      // rank among true tokens
      run += 1;
    } else {
      dest = num_tokens + (i - run);   // trues first, then falses in order
    }
    if (dest < S) perm[(size_t)b * S + dest] = i;
  }

  // Validity mask output as float 0/1.
  for (int j = t; j < S; j += 1024) {
    mask_out[(size_t)b * S + j] = (j < num_tokens) ? 1.0f : 0.0f;
  }
}

// One block per output row: grid = (S, B), 256 threads x float4 = 4 KB row.
// Nontemporal on the bulk stream: rows are touched exactly once each way,
// so bypass L2 (32 MB << 273 MB stream). Uses clang ext_vector float4 —
// __builtin_nontemporal_* rejects HIP_vector_type structs.
__global__ __launch_bounds__(256) void gather_rows(
    const float* __restrict__ hidden, const int* __restrict__ perm,
    float* __restrict__ out, int S) {
  const int r = blockIdx.x;            // 0..S-1
  const int b = blockIdx.y;            // 0..B-1
  const int t = threadIdx.x;           // one float4 slot of the row
  const int src = perm[(size_t)b * S + r];
  const nfloat4* __restrict__ in4 =
      (const nfloat4*)(hidden + ((size_t)b * LL + (size_t)src) * DD);
  nfloat4* __restrict__ out4 = (nfloat4*)(out + ((size_t)b * S + r) * DD);
  nfloat4 v = __builtin_nontemporal_load(in4 + t);
  __builtin_nontemporal_store(v, out4 + t);
}

extern "C" void kernel_launch(void* const* d_in, const int* in_sizes, int n_in,
                              void* d_out, int out_size, void* d_ws, size_t ws_size,
                              hipStream_t stream) {
  const float* hidden = (const float*)d_in[0];
  const int* mask = (const int*)d_in[1];

  // out_size = B*S*D + B*S  ->  S = out_size / (B*(D+1))
  const int S = out_size / (BB * (DD + 1));

  float* out_hidden = (float*)d_out;
  float* out_mask = out_hidden + (size_t)BB * S * DD;
  int* perm = (int*)d_ws;  // B*S ints

  build_perm<<<BB, 1024, 0, stream>>>(mask, perm, out_mask, S);
  gather_rows<<<dim3(S, BB), 256, 0, stream>>>(hidden, perm, out_hidden, S);
}